// Round 6
// baseline (352.701 us; speedup 1.0000x reference)
//
#include <hip/hip_runtime.h>
#include <math.h>

#define L 4096
#define B 8
#define D 1024
#define NH 16
#define COUT 64               // output chunk per block
#define WB 96                 // windback length (q^96 <= 6e-5 worst-case here)
#define NCHUNK (L / COUT)     // 64
#define BD 8192               // B*D floats between consecutive l

#define REP16(F) F(0) F(1) F(2) F(3) F(4) F(5) F(6) F(7) F(8) F(9) F(10) F(11) F(12) F(13) F(14) F(15)
#define REP8(F)  F(0) F(1) F(2) F(3) F(4) F(5) F(6) F(7)
#define REP4(F)  F(0) F(1) F(2) F(3)

__device__ __forceinline__ float sigmoidf(float v) {
    return 1.0f / (1.0f + __expf(-v));
}

// Flat (non-nested) per-head macros — a macro may not recursively contain the
// REP* macro that expands it (preprocessor blue paint).
#define UPD(i) s##i = fmaf(q##i, s##i, xv);
#define UPDALL UPD(0) UPD(1) UPD(2) UPD(3) UPD(4) UPD(5) UPD(6) UPD(7) \
               UPD(8) UPD(9) UPD(10) UPD(11) UPD(12) UPD(13) UPD(14) UPD(15)
#define ACC(i) s##i = fmaf(q##i, s##i, xv); y = fmaf(P##i, s##i, y);
#define ACCALL ACC(0) ACC(1) ACC(2) ACC(3) ACC(4) ACC(5) ACC(6) ACC(7) \
               ACC(8) ACC(9) ACC(10) ACC(11) ACC(12) ACC(13) ACC(14) ACC(15)

// ---------------------------------------------------------------------------
// Fully fused damped-EMA: per (b, d, chunk) thread runs the 16-head recurrence
// from (up to) WB steps before its output window with zero init (decay makes
// truncation error ~6e-5 worst case; exact for the first two chunks), then
// emits COUT outputs with projection + residual + relu. Single dispatch.
// 2048 blocks = 8 blocks/CU at 64 VGPR -> full wave-slot occupancy.
// ---------------------------------------------------------------------------
__global__ void __launch_bounds__(256, 8)
ema_fused(const float* __restrict__ x,
          const float* __restrict__ damp,
          const float* __restrict__ decay,
          const float* __restrict__ ema,
          const float* __restrict__ proj,
          const float* __restrict__ rw,
          float* __restrict__ out) {
    int d = blockIdx.x * 256 + threadIdx.x;   // 0..1023
    int c = blockIdx.y;                        // 0..NCHUNK-1
    int b = blockIdx.z;                        // 0..7

    const float* dp = damp  + d * NH;
    const float* dc = decay + d * NH;
    const float* de = ema   + d * NH;
    const float* pj = proj  + d * NH;

    // ---- state: q (decay factor) and s (per-head EMA state) ----
#define DECLQS(i) float q##i, s##i;
    REP16(DECLQS)
#define INITQS(i) { q##i = 1.0f - sigmoidf(dp[i]) * sigmoidf(dc[i]); s##i = 0.0f; }
    REP16(INITQS)

    const size_t base = (size_t)b * D + d;

    // ---- windback: advance state over [c*COUT - wb, c*COUT), 8-deep pipe ----
    int wb = c * COUT;                 // exact history available
    if (wb > WB) wb = WB;              // truncate (q^WB negligible)
    if (wb > 0) {
        const float* xp = x + (size_t)(c * COUT - wb) * BD + base;
#define LDA8(i) float a##i = xp[i * BD];
        REP8(LDA8)
        xp += 8 * BD;
        for (int r = 8; r < wb; r += 8) {
#define LDB8(i) float t##i = xp[i * BD];
            REP8(LDB8)
            xp += 8 * BD;
#define CONS8(i) { float xv = a##i; UPDALL }
            REP8(CONS8)
#define MOV8(i) a##i = t##i;
            REP8(MOV8)
        }
        REP8(CONS8)   // consume final batch
    }

    // ---- projection weights + residual weight (dead during windback) ----
#define DECLP(i) float P##i;
    REP16(DECLP)
#define INITP(i) { float p_ = sigmoidf(dp[i]); P##i = p_ * de[i] * pj[i] * 0.25f; }
    REP16(INITP)
    float w = rw[d];

    // ---- output phase: [c*COUT, (c+1)*COUT), 4-deep double-buffered ----
    const float* xp = x   + (size_t)(c * COUT) * BD + base;
    float*       op = out + (size_t)(c * COUT) * BD + base;

#define EMIT(v, k) { float xv = (v); float y = xv * w; ACCALL \
                     __builtin_nontemporal_store(fmaxf(y, 0.0f), op + (k) * BD); }

#define LDA4(i) float a##i = xp[i * BD];
    REP4(LDA4)
    xp += 4 * BD;
    for (int r = 0; r < COUT - 4; r += 4) {
#define LDB4(i) float t##i = xp[i * BD];
        REP4(LDB4)
        xp += 4 * BD;
#define EM4(i) EMIT(a##i, i)
        REP4(EM4)
        op += 4 * BD;
#define MOV4(i) a##i = t##i;
        REP4(MOV4)
    }
    REP4(EM4)   // final batch
}

// ---------------------------------------------------------------------------
extern "C" void kernel_launch(void* const* d_in, const int* in_sizes, int n_in,
                              void* d_out, int out_size, void* d_ws, size_t ws_size,
                              hipStream_t stream) {
    const float* x     = (const float*)d_in[0];
    const float* damp  = (const float*)d_in[1];
    const float* decay = (const float*)d_in[2];
    const float* ema   = (const float*)d_in[3];
    const float* proj  = (const float*)d_in[4];
    const float* rw    = (const float*)d_in[5];
    float* out = (float*)d_out;

    dim3 grid(D / 256, NCHUNK, B);
    ema_fused<<<grid, 256, 0, stream>>>(x, damp, decay, ema, proj, rw, out);
}